// Round 13
// baseline (2197.728 us; speedup 1.0000x reference)
//
#include <hip/hip_runtime.h>

#define NGROUPS 50000
#define NITEMS  100000
#define NNODES  150000
#define NEDGES  2400000
#define DIM     64
#define BROWS   128                       // rows per bucket
#define NBKT    ((NNODES + BROWS - 1) / BROWS)   // 1172
#define NPB     256                       // edge-chunk blocks for P1/P3

// round-to-nearest f32 -> bf16 (as raw ushort)
__device__ __forceinline__ ushort f2bf(float f) {
    unsigned u = __float_as_uint(f);
    u += 0x7FFF + ((u >> 16) & 1);
    return (ushort)(u >> 16);
}
__device__ __forceinline__ float bf2f(ushort h) {
    return __uint_as_float((unsigned)h << 16);
}

// ======================= bucket-binned gather path =========================

// f32 groups||items -> bf16 table x0b
__global__ __launch_bounds__(256) void k_tobf16(const float4* __restrict__ g,
                                                const float4* __restrict__ it,
                                                ushort4* __restrict__ xb) {
    const int n1 = NGROUPS * DIM / 4;
    const int n  = NNODES * DIM / 4;
    int i = blockIdx.x * blockDim.x + threadIdx.x;
    int s = gridDim.x * blockDim.x;
    for (; i < n; i += s) {
        float4 v = (i < n1) ? g[i] : it[i - n1];
        ushort4 h;
        h.x = f2bf(v.x); h.y = f2bf(v.y); h.z = f2bf(v.z); h.w = f2bf(v.w);
        xb[i] = h;
    }
}

// P1: per-block LDS bucket histogram over a fixed edge chunk (NO global
// atomics — this bypasses the ~24G/s global atomic-rtn ceiling measured
// in R8-R12). bh layout is bucket-major: bh[bucket][block].
__global__ __launch_bounds__(512) void k_bcount(const int4* __restrict__ rows4,
                                                int* __restrict__ bh) {
    __shared__ int h[NBKT];
    for (int i = threadIdx.x; i < NBKT; i += 512) h[i] = 0;
    __syncthreads();
    const int per4 = (NEDGES / 4 + NPB - 1) / NPB;   // 2344
    int b4 = blockIdx.x * per4;
    int e4 = min(b4 + per4, NEDGES / 4);
    for (int i = b4 + threadIdx.x; i < e4; i += 512) {
        int4 r = rows4[i];
        atomicAdd(&h[r.x >> 7], 1);
        atomicAdd(&h[r.y >> 7], 1);
        atomicAdd(&h[r.z >> 7], 1);
        atomicAdd(&h[r.w >> 7], 1);
    }
    __syncthreads();
    for (int i = threadIdx.x; i < NBKT; i += 512)
        bh[(size_t)i * NPB + blockIdx.x] = h[i];
}

// P2a: per-bucket exclusive scan over the NPB block counts (in place);
// bucket total -> btot. One block per bucket, NPB==256 threads.
__global__ __launch_bounds__(256) void k_bktscan(int* __restrict__ bh,
                                                 int* __restrict__ btot) {
    __shared__ int s[NPB];
    int b = blockIdx.x, t = threadIdx.x;
    int v = bh[(size_t)b * NPB + t];
    s[t] = v;
    __syncthreads();
    for (int off = 1; off < NPB; off <<= 1) {
        int u = (t >= off) ? s[t - off] : 0;
        __syncthreads();
        s[t] += u;
        __syncthreads();
    }
    bh[(size_t)b * NPB + t] = s[t] - v;   // exclusive within bucket
    if (t == NPB - 1) btot[b] = s[t];
}

// P2b: exclusive scan of btot[NBKT] -> bbase (single block, 2 elems/thread)
__global__ __launch_bounds__(1024) void k_bbase(const int* __restrict__ btot,
                                                int* __restrict__ bbase) {
    __shared__ int s[2048];
    int t = threadIdx.x;
    int v1 = (t < NBKT) ? btot[t] : 0;
    int v2 = (t + 1024 < NBKT) ? btot[t + 1024] : 0;
    s[t] = v1; s[t + 1024] = v2;
    __syncthreads();
    for (int off = 1; off < 2048; off <<= 1) {
        int u1 = (t >= off) ? s[t - off] : 0;
        int u2 = s[t + 1024 - off];       // t+1024 >= 1024 >= off always
        __syncthreads();
        s[t] += u1; s[t + 1024] += u2;
        __syncthreads();
    }
    if (t < NBKT) bbase[t] = s[t] - v1;
    if (t + 1024 < NBKT) bbase[t + 1024] = s[t + 1024] - v2;
    if (t == 0) bbase[NBKT] = NEDGES;
}

// P3: bin edges into bucket-grouped order via LDS cursors (no global
// atomics). ev[pos] = (col | row7<<18, val). Per-(block,bucket) runs are
// ~9 edges; active partial lines/XCD ~2.4MB < 4MB L2 so lines fill in L2.
__global__ __launch_bounds__(512) void k_bin(const int4* __restrict__ rows4,
                                             const int4* __restrict__ cols4,
                                             const float4* __restrict__ vals4,
                                             const int* __restrict__ bh,
                                             const int* __restrict__ bbase,
                                             int2* __restrict__ ev) {
    __shared__ int cur[NBKT];
    for (int i = threadIdx.x; i < NBKT; i += 512)
        cur[i] = bbase[i] + bh[(size_t)i * NPB + blockIdx.x];
    __syncthreads();
    const int per4 = (NEDGES / 4 + NPB - 1) / NPB;
    int b4 = blockIdx.x * per4;
    int e4 = min(b4 + per4, NEDGES / 4);
    for (int i = b4 + threadIdx.x; i < e4; i += 512) {
        int4   r = rows4[i];
        int4   c = cols4[i];
        float4 v = vals4[i];
        int p0 = atomicAdd(&cur[r.x >> 7], 1);
        int p1 = atomicAdd(&cur[r.y >> 7], 1);
        int p2 = atomicAdd(&cur[r.z >> 7], 1);
        int p3 = atomicAdd(&cur[r.w >> 7], 1);
        ev[p0] = make_int2(c.x | ((r.x & 127) << 18), __float_as_int(v.x));
        ev[p1] = make_int2(c.y | ((r.y & 127) << 18), __float_as_int(v.y));
        ev[p2] = make_int2(c.z | ((r.z & 127) << 18), __float_as_int(v.z));
        ev[p3] = make_int2(c.w | ((r.w & 127) << 18), __float_as_int(v.w));
    }
}

// ---- bucket SpMM: block owns 128 rows, f32 accumulator tile in LDS.
// Edges consumed in bucket order (any intra-order OK); quarter q of each
// wave owns one edge; 16 lanes x ushort4 = 128B = one line per gather.
// LAYER 1: gather x0b, y=x1b, out[r] = acc (r<NGROUPS)
// LAYER 2: gather x1b, y=x2b, out[r] += acc
// LAYER 3: group buckets only; gather x2b; out = (out+groups+acc)*0.25
template <int LAYER>
__global__ __launch_bounds__(512) void k_spmm_b(const int* __restrict__ bbase,
                                                const int2* __restrict__ ev,
                                                const ushort* __restrict__ xsrc,
                                                const float4* __restrict__ groups4,
                                                ushort* __restrict__ y,
                                                float4* __restrict__ out4) {
    __shared__ float acc[BROWS * DIM];    // 32 KB -> 4 blocks/CU
    float4* acc4 = (float4*)acc;
    for (int i = threadIdx.x; i < BROWS * DIM / 4; i += 512)
        acc4[i] = make_float4(0.f, 0.f, 0.f, 0.f);
    __syncthreads();

    int b     = blockIdx.x;
    int rbase = b * BROWS;
    int beg = bbase[b], end = bbase[b + 1];
    int wid = threadIdx.x >> 6, lane = threadIdx.x & 63;
    int q = lane >> 4, sl = lane & 15;

    for (int j = beg + wid * 4 + q; j < end; j += 32) {
        int2  e   = ev[j];
        int   col = e.x & 0x3FFFF;
        int   r7  = e.x >> 18;
        float v   = __int_as_float(e.y);
        ushort4 h = ((const ushort4*)(xsrc + (size_t)col * DIM))[sl];
        float* a = acc + r7 * DIM + sl * 4;
        atomicAdd(a + 0, v * bf2f(h.x));
        atomicAdd(a + 1, v * bf2f(h.y));
        atomicAdd(a + 2, v * bf2f(h.z));
        atomicAdd(a + 3, v * bf2f(h.w));
    }
    __syncthreads();

    int nrows = min(BROWS, NNODES - rbase);
    for (int i = threadIdx.x; i < nrows * 16; i += 512) {
        int rr = i >> 4, slot = i & 15;
        int r  = rbase + rr;
        float4 a = acc4[i];
        if (LAYER != 3) {
            ushort4 hh;
            hh.x = f2bf(a.x); hh.y = f2bf(a.y);
            hh.z = f2bf(a.z); hh.w = f2bf(a.w);
            ((ushort4*)(y + (size_t)r * DIM))[slot] = hh;
        }
        size_t o = (size_t)r * 16 + slot;
        if (LAYER == 1) {
            if (r < NGROUPS) out4[o] = a;
        } else if (LAYER == 2) {
            if (r < NGROUPS) {
                float4 t = out4[o];
                t.x += a.x; t.y += a.y; t.z += a.z; t.w += a.w;
                out4[o] = t;
            }
        } else {
            if (r < NGROUPS) {
                float4 t = out4[o];
                float4 g = groups4[o];
                t.x = (t.x + g.x + a.x) * 0.25f;
                t.y = (t.y + g.y + a.y) * 0.25f;
                t.z = (t.z + g.z + a.z) * 0.25f;
                t.w = (t.w + g.w + a.w) * 0.25f;
                out4[o] = t;
            }
        }
    }
}

// ====================== fallback path (atomic scatter) ======================

__global__ __launch_bounds__(256) void k_zero(float4* __restrict__ p, int n4) {
    int i = blockIdx.x * blockDim.x + threadIdx.x;
    int s = gridDim.x * blockDim.x;
    float4 z = make_float4(0.f, 0.f, 0.f, 0.f);
    for (; i < n4; i += s) p[i] = z;
}

__global__ __launch_bounds__(256) void k_concat(const float4* __restrict__ g,
                                                const float4* __restrict__ it,
                                                float4* __restrict__ x) {
    const int n1 = NGROUPS * DIM / 4;
    const int n  = NNODES * DIM / 4;
    int i = blockIdx.x * blockDim.x + threadIdx.x;
    int s = gridDim.x * blockDim.x;
    for (; i < n; i += s) x[i] = (i < n1) ? g[i] : it[i - n1];
}

__global__ __launch_bounds__(256) void k_spmm(const int*   __restrict__ rows,
                                              const int*   __restrict__ cols,
                                              const float* __restrict__ vals,
                                              const float* __restrict__ x,
                                              float*       __restrict__ y) {
    int wid  = (blockIdx.x * blockDim.x + threadIdx.x) >> 6;
    int lane = threadIdx.x & 63;
    int nw   = (gridDim.x * blockDim.x) >> 6;
    for (int e = wid; e < NEDGES; e += nw) {
        int   r = rows[e];
        int   c = cols[e];
        float v = vals[e];
        unsafeAtomicAdd(&y[r * DIM + lane], v * x[c * DIM + lane]);
    }
}

__global__ __launch_bounds__(256) void k_accum(const float4* __restrict__ src,
                                               float4* __restrict__ dst, int first) {
    const int n = NGROUPS * DIM / 4;
    int i = blockIdx.x * blockDim.x + threadIdx.x;
    int s = gridDim.x * blockDim.x;
    if (first) { for (; i < n; i += s) dst[i] = src[i]; }
    else {
        for (; i < n; i += s) {
            float4 a = dst[i], b = src[i];
            a.x += b.x; a.y += b.y; a.z += b.z; a.w += b.w;
            dst[i] = a;
        }
    }
}

__global__ __launch_bounds__(256) void k_final(const float4* __restrict__ g,
                                               float4* __restrict__ out) {
    const int n = NGROUPS * DIM / 4;
    int i = blockIdx.x * blockDim.x + threadIdx.x;
    int s = gridDim.x * blockDim.x;
    for (; i < n; i += s) {
        float4 a = out[i], b = g[i];
        out[i] = make_float4((a.x + b.x) * 0.25f, (a.y + b.y) * 0.25f,
                             (a.z + b.z) * 0.25f, (a.w + b.w) * 0.25f);
    }
}

// ===========================================================================

extern "C" void kernel_launch(void* const* d_in, const int* in_sizes, int n_in,
                              void* d_out, int out_size, void* d_ws, size_t ws_size,
                              hipStream_t stream) {
    const float* groups = (const float*)d_in[0];
    const float* items  = (const float*)d_in[1];
    const float* vals   = (const float*)d_in[2];
    const int*   rows   = (const int*)d_in[3];
    const int*   cols   = (const int*)d_in[4];
    float* out = (float*)d_out;

    // ws layout (float units)
    size_t off = 0;
    float* x1     = (float*)d_ws;               off += (size_t)NNODES * DIM;  // x1b bf16
    float* x2     = (float*)d_ws + off;         off += (size_t)NNODES * DIM;  // x2b bf16
    int2*  ev     = (int2*)((float*)d_ws + off); off += (size_t)NEDGES * 2;   // 8B-aligned
    float* x0     = (float*)d_ws + off;         off += (size_t)NNODES * DIM / 2;
    int*   bbase  = (int*)((float*)d_ws + off); off += 1280;
    int*   btot   = (int*)((float*)d_ws + off); off += 1280;
    size_t needed = off * sizeof(float);

    ushort* x0b = (ushort*)x0;
    ushort* x1b = (ushort*)x1;
    ushort* x2b = (ushort*)x2;
    // bh[NBKT][NPB] (1.2 MB) aliases the x1 region: live P1->P3 only,
    // x1b is first written by spmm_b<1> (after P3).
    int* bh = (int*)x1;

    dim3 blk(256);

    if (ws_size >= needed) {
        k_tobf16<<<1024, blk, 0, stream>>>((const float4*)groups, (const float4*)items,
                                           (ushort4*)x0b);
        // ---- bucket binning (zero global atomics) ----
        k_bcount<<<NPB, dim3(512), 0, stream>>>((const int4*)rows, bh);
        k_bktscan<<<NBKT, dim3(NPB), 0, stream>>>(bh, btot);
        k_bbase<<<1, dim3(1024), 0, stream>>>(btot, bbase);
        k_bin<<<NPB, dim3(512), 0, stream>>>((const int4*)rows, (const int4*)cols,
                                             (const float4*)vals, bh, bbase, ev);

        // ---- 3 bucket-SpMM layers, fused output accumulation ----
        const int NGB = (NGROUPS + BROWS - 1) / BROWS;   // 391
        k_spmm_b<1><<<NBKT, dim3(512), 0, stream>>>(bbase, ev, x0b,
                                                    (const float4*)groups, x1b,
                                                    (float4*)out);
        k_spmm_b<2><<<NBKT, dim3(512), 0, stream>>>(bbase, ev, x1b,
                                                    (const float4*)groups, x2b,
                                                    (float4*)out);
        k_spmm_b<3><<<NGB, dim3(512), 0, stream>>>(bbase, ev, x2b,
                                                   (const float4*)groups, nullptr,
                                                   (float4*)out);
    } else {
        // ---- fallback: proven atomic-scatter path (f32) ----
        float* xA = x1;
        float* xB = x2;
        k_concat<<<2048, blk, 0, stream>>>((const float4*)groups, (const float4*)items,
                                           (float4*)xA);
        for (int l = 0; l < 3; ++l) {
            k_zero<<<2048, blk, 0, stream>>>((float4*)xB, NNODES * DIM / 4);
            k_spmm<<<4096, blk, 0, stream>>>(rows, cols, vals, xA, xB);
            k_accum<<<512, blk, 0, stream>>>((const float4*)xB, (float4*)out, l == 0);
            float* t = xA; xA = xB; xB = t;
        }
        k_final<<<512, blk, 0, stream>>>((const float4*)groups, (float4*)out);
    }
}

// Round 14
// 330.754 us; speedup vs baseline: 6.6446x; 6.6446x over previous
//
#include <hip/hip_runtime.h>

#define NGROUPS 50000
#define NITEMS  100000
#define NNODES  150000
#define NEDGES  2400000
#define DIM     64
#define BROWS   128                              // rows per bucket
#define NBKT    ((NNODES + BROWS - 1) / BROWS)   // 1172
#define NPB     256                              // edge-chunk blocks for P1/P3

// round-to-nearest f32 -> bf16 (as raw ushort)
__device__ __forceinline__ ushort f2bf(float f) {
    unsigned u = __float_as_uint(f);
    u += 0x7FFF + ((u >> 16) & 1);
    return (ushort)(u >> 16);
}
__device__ __forceinline__ float bf2f(ushort h) {
    return __uint_as_float((unsigned)h << 16);
}

// ================== bucket-binned CSR build (no global atomics) =============

__global__ __launch_bounds__(256) void k_tobf16(const float4* __restrict__ g,
                                                const float4* __restrict__ it,
                                                ushort4* __restrict__ xb) {
    const int n1 = NGROUPS * DIM / 4;
    const int n  = NNODES * DIM / 4;
    int i = blockIdx.x * blockDim.x + threadIdx.x;
    int s = gridDim.x * blockDim.x;
    for (; i < n; i += s) {
        float4 v = (i < n1) ? g[i] : it[i - n1];
        ushort4 h;
        h.x = f2bf(v.x); h.y = f2bf(v.y); h.z = f2bf(v.z); h.w = f2bf(v.w);
        xb[i] = h;
    }
}

// P1: per-block LDS bucket histogram over a fixed edge chunk.
// bh layout bucket-major: bh[bucket][block].
__global__ __launch_bounds__(512) void k_bcount(const int4* __restrict__ rows4,
                                                int* __restrict__ bh) {
    __shared__ int h[NBKT];
    for (int i = threadIdx.x; i < NBKT; i += 512) h[i] = 0;
    __syncthreads();
    const int per4 = (NEDGES / 4 + NPB - 1) / NPB;
    int b4 = blockIdx.x * per4;
    int e4 = min(b4 + per4, NEDGES / 4);
    for (int i = b4 + threadIdx.x; i < e4; i += 512) {
        int4 r = rows4[i];
        atomicAdd(&h[r.x >> 7], 1);
        atomicAdd(&h[r.y >> 7], 1);
        atomicAdd(&h[r.z >> 7], 1);
        atomicAdd(&h[r.w >> 7], 1);
    }
    __syncthreads();
    for (int i = threadIdx.x; i < NBKT; i += 512)
        bh[(size_t)i * NPB + blockIdx.x] = h[i];
}

// P2a: per-bucket exclusive scan over NPB block counts (in place); total->btot
__global__ __launch_bounds__(256) void k_bktscan(int* __restrict__ bh,
                                                 int* __restrict__ btot) {
    __shared__ int s[NPB];
    int b = blockIdx.x, t = threadIdx.x;
    int v = bh[(size_t)b * NPB + t];
    s[t] = v;
    __syncthreads();
    for (int off = 1; off < NPB; off <<= 1) {
        int u = (t >= off) ? s[t - off] : 0;
        __syncthreads();
        s[t] += u;
        __syncthreads();
    }
    bh[(size_t)b * NPB + t] = s[t] - v;
    if (t == NPB - 1) btot[b] = s[t];
}

// P2b: exclusive scan of btot[NBKT] -> bbase
__global__ __launch_bounds__(1024) void k_bbase(const int* __restrict__ btot,
                                                int* __restrict__ bbase) {
    __shared__ int s[2048];
    int t = threadIdx.x;
    int v1 = (t < NBKT) ? btot[t] : 0;
    int v2 = (t + 1024 < NBKT) ? btot[t + 1024] : 0;
    s[t] = v1; s[t + 1024] = v2;
    __syncthreads();
    for (int off = 1; off < 2048; off <<= 1) {
        int u1 = (t >= off) ? s[t - off] : 0;
        int u2 = s[t + 1024 - off];
        __syncthreads();
        s[t] += u1; s[t + 1024] += u2;
        __syncthreads();
    }
    if (t < NBKT) bbase[t] = s[t] - v1;
    if (t + 1024 < NBKT) bbase[t + 1024] = s[t + 1024] - v2;
    if (t == 0) bbase[NBKT] = NEDGES;
}

// P3: bin edges into bucket-grouped order via LDS cursors.
// evt[pos] = (col | r7<<18, val)  (col<2^18, r7<128)
__global__ __launch_bounds__(512) void k_bin(const int4* __restrict__ rows4,
                                             const int4* __restrict__ cols4,
                                             const float4* __restrict__ vals4,
                                             const int* __restrict__ bh,
                                             const int* __restrict__ bbase,
                                             int2* __restrict__ evt) {
    __shared__ int cur[NBKT];
    for (int i = threadIdx.x; i < NBKT; i += 512)
        cur[i] = bbase[i] + bh[(size_t)i * NPB + blockIdx.x];
    __syncthreads();
    const int per4 = (NEDGES / 4 + NPB - 1) / NPB;
    int b4 = blockIdx.x * per4;
    int e4 = min(b4 + per4, NEDGES / 4);
    for (int i = b4 + threadIdx.x; i < e4; i += 512) {
        int4   r = rows4[i];
        int4   c = cols4[i];
        float4 v = vals4[i];
        int p0 = atomicAdd(&cur[r.x >> 7], 1);
        int p1 = atomicAdd(&cur[r.y >> 7], 1);
        int p2 = atomicAdd(&cur[r.z >> 7], 1);
        int p3 = atomicAdd(&cur[r.w >> 7], 1);
        evt[p0] = make_int2(c.x | ((r.x & 127) << 18), __float_as_int(v.x));
        evt[p1] = make_int2(c.y | ((r.y & 127) << 18), __float_as_int(v.y));
        evt[p2] = make_int2(c.z | ((r.z & 127) << 18), __float_as_int(v.z));
        evt[p3] = make_int2(c.w | ((r.w & 127) << 18), __float_as_int(v.w));
    }
}

// P4: second-level counting sort within each bucket (one block per bucket):
// LDS 128-row histogram -> scan -> scatter to row-sorted scv + rowptr.
// ~2 LDS atomics per edge (vs 64 in R13's failed LDS-acc SpMM).
__global__ __launch_bounds__(256) void k_sort2(const int2* __restrict__ evt,
                                               const int* __restrict__ bbase,
                                               int2* __restrict__ scv,
                                               int* __restrict__ rowptr) {
    __shared__ int h[BROWS];
    __shared__ int curp[BROWS];
    int b = blockIdx.x, t = threadIdx.x;
    int beg = bbase[b], end = bbase[b + 1];
    int rbase = b * BROWS;

    if (t < BROWS) h[t] = 0;
    __syncthreads();
    for (int j = beg + t; j < end; j += 256)
        atomicAdd(&h[evt[j].x >> 18], 1);
    __syncthreads();
    int cnt = (t < BROWS) ? h[t] : 0;
    for (int off = 1; off < BROWS; off <<= 1) {
        int u = (t < BROWS && t >= off) ? h[t - off] : 0;
        __syncthreads();
        if (t < BROWS) h[t] += u;
        __syncthreads();
    }
    if (t < BROWS) {
        int excl = beg + h[t] - cnt;
        curp[t] = excl;
        int r = rbase + t;
        if (r < NNODES) rowptr[r] = excl;
        if (r == NNODES - 1) rowptr[NNODES] = NEDGES;
    }
    __syncthreads();
    for (int j = beg + t; j < end; j += 256) {
        int2 e = evt[j];
        int  p = atomicAdd(&curp[e.x >> 18], 1);
        scv[p] = make_int2(e.x & 0x3FFFF, e.y);
    }
}

// ---- gather SpMM (proven R12 structure): one wave per row; 4 lane-quarters
// each own an edge; 16 lanes * ushort4 = 128B = one line per gather; 2-edge
// unroll -> 8 gathers in flight; register acc + shuffle combine.
template <int LAYER>
__global__ __launch_bounds__(256) void k_spmm_csr(const int* __restrict__ rowptr,
                                                  const int2* __restrict__ scv,
                                                  const ushort* __restrict__ xsrc,
                                                  const float4* __restrict__ groups4,
                                                  ushort* __restrict__ y,
                                                  float4* __restrict__ out4) {
    int r    = blockIdx.x * 4 + (threadIdx.x >> 6);
    int lane = threadIdx.x & 63;
    int q    = lane >> 4;
    int sl   = lane & 15;
    int beg = rowptr[r], end = rowptr[r + 1];

    float4 acc = make_float4(0.f, 0.f, 0.f, 0.f);
    int j = beg + q;
    for (; j + 4 < end; j += 8) {
        int2  cv0 = scv[j];
        int2  cv1 = scv[j + 4];
        float v0  = __int_as_float(cv0.y);
        float v1  = __int_as_float(cv1.y);
        ushort4 h0 = ((const ushort4*)(xsrc + (size_t)cv0.x * DIM))[sl];
        ushort4 h1 = ((const ushort4*)(xsrc + (size_t)cv1.x * DIM))[sl];
        acc.x = fmaf(v0, bf2f(h0.x), acc.x);
        acc.y = fmaf(v0, bf2f(h0.y), acc.y);
        acc.z = fmaf(v0, bf2f(h0.z), acc.z);
        acc.w = fmaf(v0, bf2f(h0.w), acc.w);
        acc.x = fmaf(v1, bf2f(h1.x), acc.x);
        acc.y = fmaf(v1, bf2f(h1.y), acc.y);
        acc.z = fmaf(v1, bf2f(h1.z), acc.z);
        acc.w = fmaf(v1, bf2f(h1.w), acc.w);
    }
    if (j < end) {
        int2  cv = scv[j];
        float v  = __int_as_float(cv.y);
        ushort4 h = ((const ushort4*)(xsrc + (size_t)cv.x * DIM))[sl];
        acc.x = fmaf(v, bf2f(h.x), acc.x);
        acc.y = fmaf(v, bf2f(h.y), acc.y);
        acc.z = fmaf(v, bf2f(h.z), acc.z);
        acc.w = fmaf(v, bf2f(h.w), acc.w);
    }
    acc.x += __shfl_xor(acc.x, 16, 64);
    acc.y += __shfl_xor(acc.y, 16, 64);
    acc.z += __shfl_xor(acc.z, 16, 64);
    acc.w += __shfl_xor(acc.w, 16, 64);
    acc.x += __shfl_xor(acc.x, 32, 64);
    acc.y += __shfl_xor(acc.y, 32, 64);
    acc.z += __shfl_xor(acc.z, 32, 64);
    acc.w += __shfl_xor(acc.w, 32, 64);

    if (lane < 16) {
        size_t o = (size_t)r * 16 + sl;
        if (LAYER != 3) {
            ushort4 h;
            h.x = f2bf(acc.x); h.y = f2bf(acc.y);
            h.z = f2bf(acc.z); h.w = f2bf(acc.w);
            ((ushort4*)(y + (size_t)r * DIM))[sl] = h;
        }
        if (LAYER == 1) {
            if (r < NGROUPS) out4[o] = acc;
        } else if (LAYER == 2) {
            if (r < NGROUPS) {
                float4 a = out4[o];
                a.x += acc.x; a.y += acc.y; a.z += acc.z; a.w += acc.w;
                out4[o] = a;
            }
        } else {
            float4 a = out4[o];
            float4 g = groups4[o];
            a.x = (a.x + g.x + acc.x) * 0.25f;
            a.y = (a.y + g.y + acc.y) * 0.25f;
            a.z = (a.z + g.z + acc.z) * 0.25f;
            a.w = (a.w + g.w + acc.w) * 0.25f;
            out4[o] = a;
        }
    }
}

// ====================== fallback path (atomic scatter) ======================

__global__ __launch_bounds__(256) void k_zero(float4* __restrict__ p, int n4) {
    int i = blockIdx.x * blockDim.x + threadIdx.x;
    int s = gridDim.x * blockDim.x;
    float4 z = make_float4(0.f, 0.f, 0.f, 0.f);
    for (; i < n4; i += s) p[i] = z;
}

__global__ __launch_bounds__(256) void k_concat(const float4* __restrict__ g,
                                                const float4* __restrict__ it,
                                                float4* __restrict__ x) {
    const int n1 = NGROUPS * DIM / 4;
    const int n  = NNODES * DIM / 4;
    int i = blockIdx.x * blockDim.x + threadIdx.x;
    int s = gridDim.x * blockDim.x;
    for (; i < n; i += s) x[i] = (i < n1) ? g[i] : it[i - n1];
}

__global__ __launch_bounds__(256) void k_spmm(const int*   __restrict__ rows,
                                              const int*   __restrict__ cols,
                                              const float* __restrict__ vals,
                                              const float* __restrict__ x,
                                              float*       __restrict__ y) {
    int wid  = (blockIdx.x * blockDim.x + threadIdx.x) >> 6;
    int lane = threadIdx.x & 63;
    int nw   = (gridDim.x * blockDim.x) >> 6;
    for (int e = wid; e < NEDGES; e += nw) {
        int   r = rows[e];
        int   c = cols[e];
        float v = vals[e];
        unsafeAtomicAdd(&y[r * DIM + lane], v * x[c * DIM + lane]);
    }
}

__global__ __launch_bounds__(256) void k_accum(const float4* __restrict__ src,
                                               float4* __restrict__ dst, int first) {
    const int n = NGROUPS * DIM / 4;
    int i = blockIdx.x * blockDim.x + threadIdx.x;
    int s = gridDim.x * blockDim.x;
    if (first) { for (; i < n; i += s) dst[i] = src[i]; }
    else {
        for (; i < n; i += s) {
            float4 a = dst[i], b = src[i];
            a.x += b.x; a.y += b.y; a.z += b.z; a.w += b.w;
            dst[i] = a;
        }
    }
}

__global__ __launch_bounds__(256) void k_final(const float4* __restrict__ g,
                                               float4* __restrict__ out) {
    const int n = NGROUPS * DIM / 4;
    int i = blockIdx.x * blockDim.x + threadIdx.x;
    int s = gridDim.x * blockDim.x;
    for (; i < n; i += s) {
        float4 a = out[i], b = g[i];
        out[i] = make_float4((a.x + b.x) * 0.25f, (a.y + b.y) * 0.25f,
                             (a.z + b.z) * 0.25f, (a.w + b.w) * 0.25f);
    }
}

// ===========================================================================

extern "C" void kernel_launch(void* const* d_in, const int* in_sizes, int n_in,
                              void* d_out, int out_size, void* d_ws, size_t ws_size,
                              hipStream_t stream) {
    const float* groups = (const float*)d_in[0];
    const float* items  = (const float*)d_in[1];
    const float* vals   = (const float*)d_in[2];
    const int*   rows   = (const int*)d_in[3];
    const int*   cols   = (const int*)d_in[4];
    float* out = (float*)d_out;

    // ws layout (float units)
    size_t off = 0;
    float* x1     = (float*)d_ws;                off += (size_t)NNODES * DIM; // x1b
    float* x2     = (float*)d_ws + off;          off += (size_t)NNODES * DIM; // x2b
    int2*  scv    = (int2*)((float*)d_ws + off); off += (size_t)NEDGES * 2;   // sorted
    float* x0     = (float*)d_ws + off;          off += (size_t)NNODES * DIM / 2;
    int*   rowptr = (int*)((float*)d_ws + off);  off += NNODES + 4;
    int*   bbase  = (int*)((float*)d_ws + off);  off += 1280;
    int*   btot   = (int*)((float*)d_ws + off);  off += 1280;
    size_t needed = off * sizeof(float);

    ushort* x0b = (ushort*)x0;
    ushort* x1b = (ushort*)x1;
    ushort* x2b = (ushort*)x2;
    // aliases (no ws growth):
    //  - bh[NBKT][NPB] (1.2MB) in x1 region: live P1->P3; x1b written by spmm<1>
    //  - evt[NEDGES] int2 (19.2MB) in x2 region: live P3->P4; x2b by spmm<2>
    int*  bh  = (int*)x1;
    int2* evt = (int2*)x2;

    dim3 blk(256);

    if (ws_size >= needed) {
        k_tobf16<<<1024, blk, 0, stream>>>((const float4*)groups, (const float4*)items,
                                           (ushort4*)x0b);
        // ---- CSR build: bucket bin + in-bucket counting sort (0 global atomics)
        k_bcount<<<NPB, dim3(512), 0, stream>>>((const int4*)rows, bh);
        k_bktscan<<<NBKT, dim3(NPB), 0, stream>>>(bh, btot);
        k_bbase<<<1, dim3(1024), 0, stream>>>(btot, bbase);
        k_bin<<<NPB, dim3(512), 0, stream>>>((const int4*)rows, (const int4*)cols,
                                             (const float4*)vals, bh, bbase, evt);
        k_sort2<<<NBKT, blk, 0, stream>>>(evt, bbase, scv, rowptr);

        // ---- 3 gather layers (proven wave-per-row structure) ----
        k_spmm_csr<1><<<NNODES / 4, blk, 0, stream>>>(rowptr, scv, x0b,
                                                      (const float4*)groups, x1b,
                                                      (float4*)out);
        k_spmm_csr<2><<<NNODES / 4, blk, 0, stream>>>(rowptr, scv, x1b,
                                                      (const float4*)groups, x2b,
                                                      (float4*)out);
        k_spmm_csr<3><<<NGROUPS / 4, blk, 0, stream>>>(rowptr, scv, x2b,
                                                       (const float4*)groups, nullptr,
                                                       (float4*)out);
    } else {
        // ---- fallback: proven atomic-scatter path (f32) ----
        float* xA = x1;
        float* xB = x2;
        k_concat<<<2048, blk, 0, stream>>>((const float4*)groups, (const float4*)items,
                                           (float4*)xA);
        for (int l = 0; l < 3; ++l) {
            k_zero<<<2048, blk, 0, stream>>>((float4*)xB, NNODES * DIM / 4);
            k_spmm<<<4096, blk, 0, stream>>>(rows, cols, vals, xA, xB);
            k_accum<<<512, blk, 0, stream>>>((const float4*)xB, (float4*)out, l == 0);
            float* t = xA; xA = xB; xB = t;
        }
        k_final<<<512, blk, 0, stream>>>((const float4*)groups, (float4*)out);
    }
}

// Round 15
// 315.705 us; speedup vs baseline: 6.9613x; 1.0477x over previous
//
#include <hip/hip_runtime.h>

#define NGROUPS 50000
#define NITEMS  100000
#define NNODES  150000
#define NEDGES  2400000
#define DIM     64
#define BROWS   128                              // rows per bucket
#define NBKT    ((NNODES + BROWS - 1) / BROWS)   // 1172
#define NPB     256                              // edge-chunk blocks for P1/P3

// round-to-nearest f32 -> bf16 (as raw ushort)
__device__ __forceinline__ ushort f2bf(float f) {
    unsigned u = __float_as_uint(f);
    u += 0x7FFF + ((u >> 16) & 1);
    return (ushort)(u >> 16);
}
__device__ __forceinline__ float bf2f(ushort h) {
    return __uint_as_float((unsigned)h << 16);
}
// packed-bf16 helpers: one int = 2 bf16
__device__ __forceinline__ float bflo(int u) { return __uint_as_float((unsigned)u << 16); }
__device__ __forceinline__ float bfhi(int u) { return __uint_as_float((unsigned)u & 0xFFFF0000u); }
__device__ __forceinline__ int pack2(float lo, float hi) {
    return (int)f2bf(lo) | ((int)f2bf(hi) << 16);
}

// ================== bucket-binned CSR build (no global atomics) =============

__global__ __launch_bounds__(256) void k_tobf16(const float4* __restrict__ g,
                                                const float4* __restrict__ it,
                                                ushort4* __restrict__ xb) {
    const int n1 = NGROUPS * DIM / 4;
    const int n  = NNODES * DIM / 4;
    int i = blockIdx.x * blockDim.x + threadIdx.x;
    int s = gridDim.x * blockDim.x;
    for (; i < n; i += s) {
        float4 v = (i < n1) ? g[i] : it[i - n1];
        ushort4 h;
        h.x = f2bf(v.x); h.y = f2bf(v.y); h.z = f2bf(v.z); h.w = f2bf(v.w);
        xb[i] = h;
    }
}

// P1: per-block LDS bucket histogram over a fixed edge chunk.
__global__ __launch_bounds__(512) void k_bcount(const int4* __restrict__ rows4,
                                                int* __restrict__ bh) {
    __shared__ int h[NBKT];
    for (int i = threadIdx.x; i < NBKT; i += 512) h[i] = 0;
    __syncthreads();
    const int per4 = (NEDGES / 4 + NPB - 1) / NPB;
    int b4 = blockIdx.x * per4;
    int e4 = min(b4 + per4, NEDGES / 4);
    for (int i = b4 + threadIdx.x; i < e4; i += 512) {
        int4 r = rows4[i];
        atomicAdd(&h[r.x >> 7], 1);
        atomicAdd(&h[r.y >> 7], 1);
        atomicAdd(&h[r.z >> 7], 1);
        atomicAdd(&h[r.w >> 7], 1);
    }
    __syncthreads();
    for (int i = threadIdx.x; i < NBKT; i += 512)
        bh[(size_t)i * NPB + blockIdx.x] = h[i];
}

// P2a: per-bucket exclusive scan over NPB block counts (in place); total->btot
__global__ __launch_bounds__(256) void k_bktscan(int* __restrict__ bh,
                                                 int* __restrict__ btot) {
    __shared__ int s[NPB];
    int b = blockIdx.x, t = threadIdx.x;
    int v = bh[(size_t)b * NPB + t];
    s[t] = v;
    __syncthreads();
    for (int off = 1; off < NPB; off <<= 1) {
        int u = (t >= off) ? s[t - off] : 0;
        __syncthreads();
        s[t] += u;
        __syncthreads();
    }
    bh[(size_t)b * NPB + t] = s[t] - v;
    if (t == NPB - 1) btot[b] = s[t];
}

// P2b: exclusive scan of btot[NBKT] -> bbase
__global__ __launch_bounds__(1024) void k_bbase(const int* __restrict__ btot,
                                                int* __restrict__ bbase) {
    __shared__ int s[2048];
    int t = threadIdx.x;
    int v1 = (t < NBKT) ? btot[t] : 0;
    int v2 = (t + 1024 < NBKT) ? btot[t + 1024] : 0;
    s[t] = v1; s[t + 1024] = v2;
    __syncthreads();
    for (int off = 1; off < 2048; off <<= 1) {
        int u1 = (t >= off) ? s[t - off] : 0;
        int u2 = s[t + 1024 - off];
        __syncthreads();
        s[t] += u1; s[t + 1024] += u2;
        __syncthreads();
    }
    if (t < NBKT) bbase[t] = s[t] - v1;
    if (t + 1024 < NBKT) bbase[t + 1024] = s[t + 1024] - v2;
    if (t == 0) bbase[NBKT] = NEDGES;
}

// P3: bin edges into bucket-grouped order via LDS cursors.
// evt[pos] = (col | r7<<18, val)
__global__ __launch_bounds__(512) void k_bin(const int4* __restrict__ rows4,
                                             const int4* __restrict__ cols4,
                                             const float4* __restrict__ vals4,
                                             const int* __restrict__ bh,
                                             const int* __restrict__ bbase,
                                             int2* __restrict__ evt) {
    __shared__ int cur[NBKT];
    for (int i = threadIdx.x; i < NBKT; i += 512)
        cur[i] = bbase[i] + bh[(size_t)i * NPB + blockIdx.x];
    __syncthreads();
    const int per4 = (NEDGES / 4 + NPB - 1) / NPB;
    int b4 = blockIdx.x * per4;
    int e4 = min(b4 + per4, NEDGES / 4);
    for (int i = b4 + threadIdx.x; i < e4; i += 512) {
        int4   r = rows4[i];
        int4   c = cols4[i];
        float4 v = vals4[i];
        int p0 = atomicAdd(&cur[r.x >> 7], 1);
        int p1 = atomicAdd(&cur[r.y >> 7], 1);
        int p2 = atomicAdd(&cur[r.z >> 7], 1);
        int p3 = atomicAdd(&cur[r.w >> 7], 1);
        evt[p0] = make_int2(c.x | ((r.x & 127) << 18), __float_as_int(v.x));
        evt[p1] = make_int2(c.y | ((r.y & 127) << 18), __float_as_int(v.y));
        evt[p2] = make_int2(c.z | ((r.z & 127) << 18), __float_as_int(v.z));
        evt[p3] = make_int2(c.w | ((r.w & 127) << 18), __float_as_int(v.w));
    }
}

// P4: in-bucket counting sort -> row-sorted scv + rowptr
__global__ __launch_bounds__(256) void k_sort2(const int2* __restrict__ evt,
                                               const int* __restrict__ bbase,
                                               int2* __restrict__ scv,
                                               int* __restrict__ rowptr) {
    __shared__ int h[BROWS];
    __shared__ int curp[BROWS];
    int b = blockIdx.x, t = threadIdx.x;
    int beg = bbase[b], end = bbase[b + 1];
    int rbase = b * BROWS;

    if (t < BROWS) h[t] = 0;
    __syncthreads();
    for (int j = beg + t; j < end; j += 256)
        atomicAdd(&h[evt[j].x >> 18], 1);
    __syncthreads();
    int cnt = (t < BROWS) ? h[t] : 0;
    for (int off = 1; off < BROWS; off <<= 1) {
        int u = (t < BROWS && t >= off) ? h[t - off] : 0;
        __syncthreads();
        if (t < BROWS) h[t] += u;
        __syncthreads();
    }
    if (t < BROWS) {
        int excl = beg + h[t] - cnt;
        curp[t] = excl;
        int r = rbase + t;
        if (r < NNODES) rowptr[r] = excl;
        if (r == NNODES - 1) rowptr[NNODES] = NEDGES;
    }
    __syncthreads();
    for (int j = beg + t; j < end; j += 256) {
        int2 e = evt[j];
        int  p = atomicAdd(&curp[e.x >> 18], 1);
        scv[p] = make_int2(e.x & 0x3FFFF, e.y);
    }
}

// ---- gather SpMM: one wave per row; 8 lane-slices (8 lanes x int4=16B) each
// own an edge -> 8 edges in flight, 2-deep unroll -> 16 outstanding 16B
// gathers/wave. scv reads per unroll-half are 8 consecutive int2 = one 64B
// line. Register acc (8 f32/lane) + 3-round shuffle combine.
template <int LAYER>
__global__ __launch_bounds__(256) void k_spmm_csr(const int* __restrict__ rowptr,
                                                  const int2* __restrict__ scv,
                                                  const ushort* __restrict__ xsrc,
                                                  const float4* __restrict__ groups4,
                                                  ushort* __restrict__ y,
                                                  float4* __restrict__ out4) {
    int r    = blockIdx.x * 4 + (threadIdx.x >> 6);
    int lane = threadIdx.x & 63;
    int q    = lane >> 3;     // slice 0..7 — which edge of a group of 8
    int sl   = lane & 7;      // int4 (16B) slot within the 128B row
    int beg = rowptr[r], end = rowptr[r + 1];

    float a0 = 0.f, a1 = 0.f, a2 = 0.f, a3 = 0.f;
    float a4 = 0.f, a5 = 0.f, a6 = 0.f, a7 = 0.f;

    int j = beg + q;
    for (; j + 8 < end; j += 16) {
        int2  cv0 = scv[j];
        int2  cv1 = scv[j + 8];
        float v0  = __int_as_float(cv0.y);
        float v1  = __int_as_float(cv1.y);
        int4 h0 = ((const int4*)(xsrc + (size_t)cv0.x * DIM))[sl];
        int4 h1 = ((const int4*)(xsrc + (size_t)cv1.x * DIM))[sl];
        a0 = fmaf(v0, bflo(h0.x), a0); a1 = fmaf(v0, bfhi(h0.x), a1);
        a2 = fmaf(v0, bflo(h0.y), a2); a3 = fmaf(v0, bfhi(h0.y), a3);
        a4 = fmaf(v0, bflo(h0.z), a4); a5 = fmaf(v0, bfhi(h0.z), a5);
        a6 = fmaf(v0, bflo(h0.w), a6); a7 = fmaf(v0, bfhi(h0.w), a7);
        a0 = fmaf(v1, bflo(h1.x), a0); a1 = fmaf(v1, bfhi(h1.x), a1);
        a2 = fmaf(v1, bflo(h1.y), a2); a3 = fmaf(v1, bfhi(h1.y), a3);
        a4 = fmaf(v1, bflo(h1.z), a4); a5 = fmaf(v1, bfhi(h1.z), a5);
        a6 = fmaf(v1, bflo(h1.w), a6); a7 = fmaf(v1, bfhi(h1.w), a7);
    }
    if (j < end) {
        int2  cv = scv[j];
        float v  = __int_as_float(cv.y);
        int4 h = ((const int4*)(xsrc + (size_t)cv.x * DIM))[sl];
        a0 = fmaf(v, bflo(h.x), a0); a1 = fmaf(v, bfhi(h.x), a1);
        a2 = fmaf(v, bflo(h.y), a2); a3 = fmaf(v, bfhi(h.y), a3);
        a4 = fmaf(v, bflo(h.z), a4); a5 = fmaf(v, bfhi(h.z), a5);
        a6 = fmaf(v, bflo(h.w), a6); a7 = fmaf(v, bfhi(h.w), a7);
    }

    // combine the 8 slices (xor over q bits 3..5); every lane ends with the
    // full sums for its sl's 8 dims
    #define RED1(a) a += __shfl_xor(a, 8, 64); a += __shfl_xor(a, 16, 64); a += __shfl_xor(a, 32, 64);
    RED1(a0) RED1(a1) RED1(a2) RED1(a3) RED1(a4) RED1(a5) RED1(a6) RED1(a7)
    #undef RED1

    if (lane < 16) {
        int half = lane >> 3;          // 0: dims sl*8+0..3, 1: dims sl*8+4..7
        float b0 = half ? a4 : a0, b1 = half ? a5 : a1;
        float b2 = half ? a6 : a2, b3 = half ? a7 : a3;
        if (LAYER != 3) {
            int2 w;
            w.x = pack2(b0, b1);
            w.y = pack2(b2, b3);
            ((int2*)(y + (size_t)r * DIM))[sl * 2 + half] = w;
        }
        size_t o = (size_t)r * 16 + sl * 2 + half;   // float4 slot
        if (LAYER == 1) {
            if (r < NGROUPS) out4[o] = make_float4(b0, b1, b2, b3);
        } else if (LAYER == 2) {
            if (r < NGROUPS) {
                float4 a = out4[o];
                a.x += b0; a.y += b1; a.z += b2; a.w += b3;
                out4[o] = a;
            }
        } else {
            float4 a = out4[o];
            float4 g = groups4[o];
            a.x = (a.x + g.x + b0) * 0.25f;
            a.y = (a.y + g.y + b1) * 0.25f;
            a.z = (a.z + g.z + b2) * 0.25f;
            a.w = (a.w + g.w + b3) * 0.25f;
            out4[o] = a;
        }
    }
}

// ====================== fallback path (atomic scatter) ======================

__global__ __launch_bounds__(256) void k_zero(float4* __restrict__ p, int n4) {
    int i = blockIdx.x * blockDim.x + threadIdx.x;
    int s = gridDim.x * blockDim.x;
    float4 z = make_float4(0.f, 0.f, 0.f, 0.f);
    for (; i < n4; i += s) p[i] = z;
}

__global__ __launch_bounds__(256) void k_concat(const float4* __restrict__ g,
                                                const float4* __restrict__ it,
                                                float4* __restrict__ x) {
    const int n1 = NGROUPS * DIM / 4;
    const int n  = NNODES * DIM / 4;
    int i = blockIdx.x * blockDim.x + threadIdx.x;
    int s = gridDim.x * blockDim.x;
    for (; i < n; i += s) x[i] = (i < n1) ? g[i] : it[i - n1];
}

__global__ __launch_bounds__(256) void k_spmm(const int*   __restrict__ rows,
                                              const int*   __restrict__ cols,
                                              const float* __restrict__ vals,
                                              const float* __restrict__ x,
                                              float*       __restrict__ y) {
    int wid  = (blockIdx.x * blockDim.x + threadIdx.x) >> 6;
    int lane = threadIdx.x & 63;
    int nw   = (gridDim.x * blockDim.x) >> 6;
    for (int e = wid; e < NEDGES; e += nw) {
        int   r = rows[e];
        int   c = cols[e];
        float v = vals[e];
        unsafeAtomicAdd(&y[r * DIM + lane], v * x[c * DIM + lane]);
    }
}

__global__ __launch_bounds__(256) void k_accum(const float4* __restrict__ src,
                                               float4* __restrict__ dst, int first) {
    const int n = NGROUPS * DIM / 4;
    int i = blockIdx.x * blockDim.x + threadIdx.x;
    int s = gridDim.x * blockDim.x;
    if (first) { for (; i < n; i += s) dst[i] = src[i]; }
    else {
        for (; i < n; i += s) {
            float4 a = dst[i], b = src[i];
            a.x += b.x; a.y += b.y; a.z += b.z; a.w += b.w;
            dst[i] = a;
        }
    }
}

__global__ __launch_bounds__(256) void k_final(const float4* __restrict__ g,
                                               float4* __restrict__ out) {
    const int n = NGROUPS * DIM / 4;
    int i = blockIdx.x * blockDim.x + threadIdx.x;
    int s = gridDim.x * blockDim.x;
    for (; i < n; i += s) {
        float4 a = out[i], b = g[i];
        out[i] = make_float4((a.x + b.x) * 0.25f, (a.y + b.y) * 0.25f,
                             (a.z + b.z) * 0.25f, (a.w + b.w) * 0.25f);
    }
}

// ===========================================================================

extern "C" void kernel_launch(void* const* d_in, const int* in_sizes, int n_in,
                              void* d_out, int out_size, void* d_ws, size_t ws_size,
                              hipStream_t stream) {
    const float* groups = (const float*)d_in[0];
    const float* items  = (const float*)d_in[1];
    const float* vals   = (const float*)d_in[2];
    const int*   rows   = (const int*)d_in[3];
    const int*   cols   = (const int*)d_in[4];
    float* out = (float*)d_out;

    // ws layout (float units)
    size_t off = 0;
    float* x1     = (float*)d_ws;                off += (size_t)NNODES * DIM; // x1b
    float* x2     = (float*)d_ws + off;          off += (size_t)NNODES * DIM; // x2b
    int2*  scv    = (int2*)((float*)d_ws + off); off += (size_t)NEDGES * 2;   // sorted
    float* x0     = (float*)d_ws + off;          off += (size_t)NNODES * DIM / 2;
    int*   rowptr = (int*)((float*)d_ws + off);  off += NNODES + 4;
    int*   bbase  = (int*)((float*)d_ws + off);  off += 1280;
    int*   btot   = (int*)((float*)d_ws + off);  off += 1280;
    size_t needed = off * sizeof(float);

    ushort* x0b = (ushort*)x0;
    ushort* x1b = (ushort*)x1;
    ushort* x2b = (ushort*)x2;
    // aliases (no ws growth):
    //  - bh[NBKT][NPB] (1.2MB) in x1 region: live P1->P3; x1b written by spmm<1>
    //  - evt[NEDGES] int2 (19.2MB) in x2 region: live P3->P4; x2b by spmm<2>
    int*  bh  = (int*)x1;
    int2* evt = (int2*)x2;

    dim3 blk(256);

    if (ws_size >= needed) {
        k_tobf16<<<1024, blk, 0, stream>>>((const float4*)groups, (const float4*)items,
                                           (ushort4*)x0b);
        // ---- CSR build: bucket bin + in-bucket counting sort (0 global atomics)
        k_bcount<<<NPB, dim3(512), 0, stream>>>((const int4*)rows, bh);
        k_bktscan<<<NBKT, dim3(NPB), 0, stream>>>(bh, btot);
        k_bbase<<<1, dim3(1024), 0, stream>>>(btot, bbase);
        k_bin<<<NPB, dim3(512), 0, stream>>>((const int4*)rows, (const int4*)cols,
                                             (const float4*)vals, bh, bbase, evt);
        k_sort2<<<NBKT, blk, 0, stream>>>(evt, bbase, scv, rowptr);

        // ---- 3 gather layers ----
        k_spmm_csr<1><<<NNODES / 4, blk, 0, stream>>>(rowptr, scv, x0b,
                                                      (const float4*)groups, x1b,
                                                      (float4*)out);
        k_spmm_csr<2><<<NNODES / 4, blk, 0, stream>>>(rowptr, scv, x1b,
                                                      (const float4*)groups, x2b,
                                                      (float4*)out);
        k_spmm_csr<3><<<NGROUPS / 4, blk, 0, stream>>>(rowptr, scv, x2b,
                                                       (const float4*)groups, nullptr,
                                                       (float4*)out);
    } else {
        // ---- fallback: proven atomic-scatter path (f32) ----
        float* xA = x1;
        float* xB = x2;
        k_concat<<<2048, blk, 0, stream>>>((const float4*)groups, (const float4*)items,
                                           (float4*)xA);
        for (int l = 0; l < 3; ++l) {
            k_zero<<<2048, blk, 0, stream>>>((float4*)xB, NNODES * DIM / 4);
            k_spmm<<<4096, blk, 0, stream>>>(rows, cols, vals, xA, xB);
            k_accum<<<512, blk, 0, stream>>>((const float4*)xB, (float4*)out, l == 0);
            float* t = xA; xA = xB; xB = t;
        }
        k_final<<<512, blk, 0, stream>>>((const float4*)groups, (float4*)out);
    }
}

// Round 17
// 303.145 us; speedup vs baseline: 7.2498x; 1.0414x over previous
//
#include <hip/hip_runtime.h>

#define NGROUPS 50000
#define NITEMS  100000
#define NNODES  150000
#define NEDGES  2400000
#define DIM     64
#define BROWS   128                              // rows per bucket
#define NBKT    ((NNODES + BROWS - 1) / BROWS)   // 1172
#define NPB     256                              // edge-chunk blocks for P1/P3

// round-to-nearest f32 -> bf16 (as raw ushort)
__device__ __forceinline__ ushort f2bf(float f) {
    unsigned u = __float_as_uint(f);
    u += 0x7FFF + ((u >> 16) & 1);
    return (ushort)(u >> 16);
}
__device__ __forceinline__ float bf2f(ushort h) {
    return __uint_as_float((unsigned)h << 16);
}
// packed-bf16 helpers: one int = 2 bf16
__device__ __forceinline__ float bflo(int u) { return __uint_as_float((unsigned)u << 16); }
__device__ __forceinline__ float bfhi(int u) { return __uint_as_float((unsigned)u & 0xFFFF0000u); }
__device__ __forceinline__ int pack2(float lo, float hi) {
    return (int)f2bf(lo) | ((int)f2bf(hi) << 16);
}

// ================== bucket-binned CSR build (no global atomics) =============

__global__ __launch_bounds__(256) void k_tobf16(const float4* __restrict__ g,
                                                const float4* __restrict__ it,
                                                ushort4* __restrict__ xb) {
    const int n1 = NGROUPS * DIM / 4;
    const int n  = NNODES * DIM / 4;
    int i = blockIdx.x * blockDim.x + threadIdx.x;
    int s = gridDim.x * blockDim.x;
    for (; i < n; i += s) {
        float4 v = (i < n1) ? g[i] : it[i - n1];
        ushort4 h;
        h.x = f2bf(v.x); h.y = f2bf(v.y); h.z = f2bf(v.z); h.w = f2bf(v.w);
        xb[i] = h;
    }
}

// P1: per-block LDS bucket histogram over a fixed edge chunk.
__global__ __launch_bounds__(512) void k_bcount(const int4* __restrict__ rows4,
                                                int* __restrict__ bh) {
    __shared__ int h[NBKT];
    for (int i = threadIdx.x; i < NBKT; i += 512) h[i] = 0;
    __syncthreads();
    const int per4 = (NEDGES / 4 + NPB - 1) / NPB;
    int b4 = blockIdx.x * per4;
    int e4 = min(b4 + per4, NEDGES / 4);
    for (int i = b4 + threadIdx.x; i < e4; i += 512) {
        int4 r = rows4[i];
        atomicAdd(&h[r.x >> 7], 1);
        atomicAdd(&h[r.y >> 7], 1);
        atomicAdd(&h[r.z >> 7], 1);
        atomicAdd(&h[r.w >> 7], 1);
    }
    __syncthreads();
    for (int i = threadIdx.x; i < NBKT; i += 512)
        bh[(size_t)i * NPB + blockIdx.x] = h[i];
}

// P2a: per-bucket exclusive scan over NPB block counts (in place); total->btot
__global__ __launch_bounds__(256) void k_bktscan(int* __restrict__ bh,
                                                 int* __restrict__ btot) {
    __shared__ int s[NPB];
    int b = blockIdx.x, t = threadIdx.x;
    int v = bh[(size_t)b * NPB + t];
    s[t] = v;
    __syncthreads();
    for (int off = 1; off < NPB; off <<= 1) {
        int u = (t >= off) ? s[t - off] : 0;
        __syncthreads();
        s[t] += u;
        __syncthreads();
    }
    bh[(size_t)b * NPB + t] = s[t] - v;
    if (t == NPB - 1) btot[b] = s[t];
}

// P2b: exclusive scan of btot[NBKT] -> bbase
__global__ __launch_bounds__(1024) void k_bbase(const int* __restrict__ btot,
                                                int* __restrict__ bbase) {
    __shared__ int s[2048];
    int t = threadIdx.x;
    int v1 = (t < NBKT) ? btot[t] : 0;
    int v2 = (t + 1024 < NBKT) ? btot[t + 1024] : 0;
    s[t] = v1; s[t + 1024] = v2;
    __syncthreads();
    for (int off = 1; off < 2048; off <<= 1) {
        int u1 = (t >= off) ? s[t - off] : 0;
        int u2 = s[t + 1024 - off];
        __syncthreads();
        s[t] += u1; s[t + 1024] += u2;
        __syncthreads();
    }
    if (t < NBKT) bbase[t] = s[t] - v1;
    if (t + 1024 < NBKT) bbase[t + 1024] = s[t + 1024] - v2;
    if (t == 0) bbase[NBKT] = NEDGES;
}

// P3: bin edges into bucket-grouped order via LDS cursors.
// evt[pos] = (col | r7<<18, val)
__global__ __launch_bounds__(512) void k_bin(const int4* __restrict__ rows4,
                                             const int4* __restrict__ cols4,
                                             const float4* __restrict__ vals4,
                                             const int* __restrict__ bh,
                                             const int* __restrict__ bbase,
                                             int2* __restrict__ evt) {
    __shared__ int cur[NBKT];
    for (int i = threadIdx.x; i < NBKT; i += 512)
        cur[i] = bbase[i] + bh[(size_t)i * NPB + blockIdx.x];
    __syncthreads();
    const int per4 = (NEDGES / 4 + NPB - 1) / NPB;
    int b4 = blockIdx.x * per4;
    int e4 = min(b4 + per4, NEDGES / 4);
    for (int i = b4 + threadIdx.x; i < e4; i += 512) {
        int4   r = rows4[i];
        int4   c = cols4[i];
        float4 v = vals4[i];
        int p0 = atomicAdd(&cur[r.x >> 7], 1);
        int p1 = atomicAdd(&cur[r.y >> 7], 1);
        int p2 = atomicAdd(&cur[r.z >> 7], 1);
        int p3 = atomicAdd(&cur[r.w >> 7], 1);
        evt[p0] = make_int2(c.x | ((r.x & 127) << 18), __float_as_int(v.x));
        evt[p1] = make_int2(c.y | ((r.y & 127) << 18), __float_as_int(v.y));
        evt[p2] = make_int2(c.z | ((r.z & 127) << 18), __float_as_int(v.z));
        evt[p3] = make_int2(c.w | ((r.w & 127) << 18), __float_as_int(v.w));
    }
}

// P4: in-bucket counting sort -> row-sorted scv + rowptr
__global__ __launch_bounds__(256) void k_sort2(const int2* __restrict__ evt,
                                               const int* __restrict__ bbase,
                                               int2* __restrict__ scv,
                                               int* __restrict__ rowptr) {
    __shared__ int h[BROWS];
    __shared__ int curp[BROWS];
    int b = blockIdx.x, t = threadIdx.x;
    int beg = bbase[b], end = bbase[b + 1];
    int rbase = b * BROWS;

    if (t < BROWS) h[t] = 0;
    __syncthreads();
    for (int j = beg + t; j < end; j += 256)
        atomicAdd(&h[evt[j].x >> 18], 1);
    __syncthreads();
    int cnt = (t < BROWS) ? h[t] : 0;
    for (int off = 1; off < BROWS; off <<= 1) {
        int u = (t < BROWS && t >= off) ? h[t - off] : 0;
        __syncthreads();
        if (t < BROWS) h[t] += u;
        __syncthreads();
    }
    if (t < BROWS) {
        int excl = beg + h[t] - cnt;
        curp[t] = excl;
        int r = rbase + t;
        if (r < NNODES) rowptr[r] = excl;
        if (r == NNODES - 1) rowptr[NNODES] = NEDGES;
    }
    __syncthreads();
    for (int j = beg + t; j < end; j += 256) {
        int2 e = evt[j];
        int  p = atomicAdd(&curp[e.x >> 18], 1);
        scv[p] = make_int2(e.x & 0x3FFFF, e.y);
    }
}

// ---- gather SpMM: one ROW per 8-lane slice (8 rows per wave). Slice walks
// its row's edges serially: lane loads int4=16B of the gathered row; 2-deep
// unroll -> 16 outstanding 16B gathers/wave. NO cross-lane reduction (the
// R15 profile showed the 24-shuffle butterfly cost more than the compute).
// Epilogue: every lane stores its 8 dims directly.
template <int LAYER>
__global__ __launch_bounds__(256) void k_spmm_csr(const int* __restrict__ rowptr,
                                                  const int2* __restrict__ scv,
                                                  const ushort* __restrict__ xsrc,
                                                  const float4* __restrict__ groups4,
                                                  ushort* __restrict__ y,
                                                  float4* __restrict__ out4) {
    int wid   = threadIdx.x >> 6;
    int lane  = threadIdx.x & 63;
    int slice = lane >> 3;    // 0..7: which row of the wave's group of 8
    int sl    = lane & 7;     // int4 (16B) slot within the 128B row

    int r = blockIdx.x * 32 + wid * 8 + slice;
    const int RLIM = (LAYER == 3) ? NGROUPS : NNODES;
    if (r >= RLIM) return;
    int beg = rowptr[r], end = rowptr[r + 1];

    float a0 = 0.f, a1 = 0.f, a2 = 0.f, a3 = 0.f;
    float a4 = 0.f, a5 = 0.f, a6 = 0.f, a7 = 0.f;

    int j = beg;
    for (; j + 1 < end; j += 2) {
        int2  cv0 = scv[j];
        int2  cv1 = scv[j + 1];
        float v0  = __int_as_float(cv0.y);
        float v1  = __int_as_float(cv1.y);
        int4 h0 = ((const int4*)(xsrc + (size_t)cv0.x * DIM))[sl];
        int4 h1 = ((const int4*)(xsrc + (size_t)cv1.x * DIM))[sl];
        a0 = fmaf(v0, bflo(h0.x), a0); a1 = fmaf(v0, bfhi(h0.x), a1);
        a2 = fmaf(v0, bflo(h0.y), a2); a3 = fmaf(v0, bfhi(h0.y), a3);
        a4 = fmaf(v0, bflo(h0.z), a4); a5 = fmaf(v0, bfhi(h0.z), a5);
        a6 = fmaf(v0, bflo(h0.w), a6); a7 = fmaf(v0, bfhi(h0.w), a7);
        a0 = fmaf(v1, bflo(h1.x), a0); a1 = fmaf(v1, bfhi(h1.x), a1);
        a2 = fmaf(v1, bflo(h1.y), a2); a3 = fmaf(v1, bfhi(h1.y), a3);
        a4 = fmaf(v1, bflo(h1.z), a4); a5 = fmaf(v1, bfhi(h1.z), a5);
        a6 = fmaf(v1, bflo(h1.w), a6); a7 = fmaf(v1, bfhi(h1.w), a7);
    }
    if (j < end) {
        int2  cv = scv[j];
        float v  = __int_as_float(cv.y);
        int4 h = ((const int4*)(xsrc + (size_t)cv.x * DIM))[sl];
        a0 = fmaf(v, bflo(h.x), a0); a1 = fmaf(v, bfhi(h.x), a1);
        a2 = fmaf(v, bflo(h.y), a2); a3 = fmaf(v, bfhi(h.y), a3);
        a4 = fmaf(v, bflo(h.z), a4); a5 = fmaf(v, bfhi(h.z), a5);
        a6 = fmaf(v, bflo(h.w), a6); a7 = fmaf(v, bfhi(h.w), a7);
    }

    if (LAYER != 3) {
        int4 w;
        w.x = pack2(a0, a1); w.y = pack2(a2, a3);
        w.z = pack2(a4, a5); w.w = pack2(a6, a7);
        ((int4*)(y + (size_t)r * DIM))[sl] = w;
    }
    size_t o = (size_t)r * 16 + sl * 2;   // float4 slot of dims sl*8..sl*8+3
    if (LAYER == 1) {
        if (r < NGROUPS) {
            out4[o]     = make_float4(a0, a1, a2, a3);
            out4[o + 1] = make_float4(a4, a5, a6, a7);
        }
    } else if (LAYER == 2) {
        if (r < NGROUPS) {
            float4 p = out4[o], q = out4[o + 1];
            p.x += a0; p.y += a1; p.z += a2; p.w += a3;
            q.x += a4; q.y += a5; q.z += a6; q.w += a7;
            out4[o] = p; out4[o + 1] = q;
        }
    } else {
        float4 p = out4[o], q = out4[o + 1];
        float4 gp = groups4[o], gq = groups4[o + 1];
        p.x = (p.x + gp.x + a0) * 0.25f;
        p.y = (p.y + gp.y + a1) * 0.25f;
        p.z = (p.z + gp.z + a2) * 0.25f;
        p.w = (p.w + gp.w + a3) * 0.25f;
        q.x = (q.x + gq.x + a4) * 0.25f;
        q.y = (q.y + gq.y + a5) * 0.25f;
        q.z = (q.z + gq.z + a6) * 0.25f;
        q.w = (q.w + gq.w + a7) * 0.25f;
        out4[o] = p; out4[o + 1] = q;
    }
}

// ====================== fallback path (atomic scatter) ======================

__global__ __launch_bounds__(256) void k_zero(float4* __restrict__ p, int n4) {
    int i = blockIdx.x * blockDim.x + threadIdx.x;
    int s = gridDim.x * blockDim.x;
    float4 z = make_float4(0.f, 0.f, 0.f, 0.f);
    for (; i < n4; i += s) p[i] = z;
}

__global__ __launch_bounds__(256) void k_concat(const float4* __restrict__ g,
                                                const float4* __restrict__ it,
                                                float4* __restrict__ x) {
    const int n1 = NGROUPS * DIM / 4;
    const int n  = NNODES * DIM / 4;
    int i = blockIdx.x * blockDim.x + threadIdx.x;
    int s = gridDim.x * blockDim.x;
    for (; i < n; i += s) x[i] = (i < n1) ? g[i] : it[i - n1];
}

__global__ __launch_bounds__(256) void k_spmm(const int*   __restrict__ rows,
                                              const int*   __restrict__ cols,
                                              const float* __restrict__ vals,
                                              const float* __restrict__ x,
                                              float*       __restrict__ y) {
    int wid  = (blockIdx.x * blockDim.x + threadIdx.x) >> 6;
    int lane = threadIdx.x & 63;
    int nw   = (gridDim.x * blockDim.x) >> 6;
    for (int e = wid; e < NEDGES; e += nw) {
        int   r = rows[e];
        int   c = cols[e];
        float v = vals[e];
        unsafeAtomicAdd(&y[r * DIM + lane], v * x[c * DIM + lane]);
    }
}

__global__ __launch_bounds__(256) void k_accum(const float4* __restrict__ src,
                                               float4* __restrict__ dst, int first) {
    const int n = NGROUPS * DIM / 4;
    int i = blockIdx.x * blockDim.x + threadIdx.x;
    int s = gridDim.x * blockDim.x;
    if (first) { for (; i < n; i += s) dst[i] = src[i]; }
    else {
        for (; i < n; i += s) {
            float4 a = dst[i], b = src[i];
            a.x += b.x; a.y += b.y; a.z += b.z; a.w += b.w;
            dst[i] = a;
        }
    }
}

__global__ __launch_bounds__(256) void k_final(const float4* __restrict__ g,
                                               float4* __restrict__ out) {
    const int n = NGROUPS * DIM / 4;
    int i = blockIdx.x * blockDim.x + threadIdx.x;
    int s = gridDim.x * blockDim.x;
    for (; i < n; i += s) {
        float4 a = out[i], b = g[i];
        out[i] = make_float4((a.x + b.x) * 0.25f, (a.y + b.y) * 0.25f,
                             (a.z + b.z) * 0.25f, (a.w + b.w) * 0.25f);
    }
}

// ===========================================================================

extern "C" void kernel_launch(void* const* d_in, const int* in_sizes, int n_in,
                              void* d_out, int out_size, void* d_ws, size_t ws_size,
                              hipStream_t stream) {
    const float* groups = (const float*)d_in[0];
    const float* items  = (const float*)d_in[1];
    const float* vals   = (const float*)d_in[2];
    const int*   rows   = (const int*)d_in[3];
    const int*   cols   = (const int*)d_in[4];
    float* out = (float*)d_out;

    // ws layout (float units)
    size_t off = 0;
    float* x1     = (float*)d_ws;                off += (size_t)NNODES * DIM; // x1b
    float* x2     = (float*)d_ws + off;          off += (size_t)NNODES * DIM; // x2b
    int2*  scv    = (int2*)((float*)d_ws + off); off += (size_t)NEDGES * 2;   // sorted
    float* x0     = (float*)d_ws + off;          off += (size_t)NNODES * DIM / 2;
    int*   rowptr = (int*)((float*)d_ws + off);  off += NNODES + 4;
    int*   bbase  = (int*)((float*)d_ws + off);  off += 1280;
    int*   btot   = (int*)((float*)d_ws + off);  off += 1280;
    size_t needed = off * sizeof(float);

    ushort* x0b = (ushort*)x0;
    ushort* x1b = (ushort*)x1;
    ushort* x2b = (ushort*)x2;
    // aliases (no ws growth):
    //  - bh[NBKT][NPB] (1.2MB) in x1 region: live P1->P3; x1b written by spmm<1>
    //  - evt[NEDGES] int2 (19.2MB) in x2 region: live P3->P4; x2b by spmm<2>
    int*  bh  = (int*)x1;
    int2* evt = (int2*)x2;

    dim3 blk(256);

    if (ws_size >= needed) {
        k_tobf16<<<1024, blk, 0, stream>>>((const float4*)groups, (const float4*)items,
                                           (ushort4*)x0b);
        // ---- CSR build: bucket bin + in-bucket counting sort (0 global atomics)
        k_bcount<<<NPB, dim3(512), 0, stream>>>((const int4*)rows, bh);
        k_bktscan<<<NBKT, dim3(NPB), 0, stream>>>(bh, btot);
        k_bbase<<<1, dim3(1024), 0, stream>>>(btot, bbase);
        k_bin<<<NPB, dim3(512), 0, stream>>>((const int4*)rows, (const int4*)cols,
                                             (const float4*)vals, bh, bbase, evt);
        k_sort2<<<NBKT, blk, 0, stream>>>(evt, bbase, scv, rowptr);

        // ---- 3 gather layers (8 rows per wave, no reduction) ----
        const int GB1 = (NNODES + 31) / 32;    // 4688
        const int GB3 = (NGROUPS + 31) / 32;   // 1563
        k_spmm_csr<1><<<GB1, blk, 0, stream>>>(rowptr, scv, x0b,
                                               (const float4*)groups, x1b,
                                               (float4*)out);
        k_spmm_csr<2><<<GB1, blk, 0, stream>>>(rowptr, scv, x1b,
                                               (const float4*)groups, x2b,
                                               (float4*)out);
        k_spmm_csr<3><<<GB3, blk, 0, stream>>>(rowptr, scv, x2b,
                                               (const float4*)groups, nullptr,
                                               (float4*)out);
    } else {
        // ---- fallback: proven atomic-scatter path (f32) ----
        float* xA = x1;
        float* xB = x2;
        k_concat<<<2048, blk, 0, stream>>>((const float4*)groups, (const float4*)items,
                                           (float4*)xA);
        for (int l = 0; l < 3; ++l) {
            k_zero<<<2048, blk, 0, stream>>>((float4*)xB, NNODES * DIM / 4);
            k_spmm<<<4096, blk, 0, stream>>>(rows, cols, vals, xA, xB);
            k_accum<<<512, blk, 0, stream>>>((const float4*)xB, (float4*)out, l == 0);
            float* t = xA; xA = xB; xB = t;
        }
        k_final<<<512, blk, 0, stream>>>((const float4*)groups, (float4*)out);
    }
}